// Round 9
// baseline (62.199 us; speedup 1.0000x reference)
//
#include <hip/hip_runtime.h>

// TokenEmbedding_51153060495497
// x: (256, 512, 7) f32;  kernels: (74, 8, 3) f32; keff = kernels[:,:,1]
// out flat: (256*513, 512) f32
//   row r = b*513 + t;  f in [0,512):
//     f < 511 : c = f/73, k = f%73
//     f == 511: c = 0,    k = 73
//   out[r*512+f] = sum_j xp[b, t+j-4, c] * keff[k, j]  (xp zero outside [0,512))
//
// Quad version with LDS channel-pair duplication: each thread owns 4 outputs
// (f = 4q .. 4q+3) as two pairs. LDS holds, per window row, the 11 canonical
// channel pairs {(0,0)..(6,6),(0,1),(2,3),(4,5),(6,0)} so each pair's two
// window values are one aligned ds_read_b64. 16 pk_fma per step, all slots
// useful; ONE dwordx4 store per step -> 16B/lane store stream.

typedef float v2f __attribute__((ext_vector_type(2)));
typedef float v4f __attribute__((ext_vector_type(4)));

#define CDIM 7
#define TROWS 513
#define CHUNK 64
#define WIN_ROWS 72                    // CHUNK + 8
#define RAW_ELEMS (WIN_ROWS * CDIM)    // 504 floats = 126 float4
#define NPAIRS 11
#define PAIR_ITEMS (WIN_ROWS * NPAIRS) // 792

__device__ __forceinline__ int chan_of(int f) { return (f == 511) ? 0 : (f / 73); }
__device__ __forceinline__ int kidx_of(int f) { return (f == 511) ? 73 : (f % 73); }
// descriptor for output pair (f, f+1) -> canonical pair index
__device__ __forceinline__ int pair_m(int f) {
  const int cA = chan_of(f), cB = chan_of(f + 1);
  return (cA == cB) ? cA : (cA == 6 ? 10 : 7 + (cA >> 1));
}

__global__ __launch_bounds__(256, 5) void tok_conv_kernel(
    const float* __restrict__ x,     // (256,512,7)
    const float* __restrict__ kern,  // (74,8,3)
    float* __restrict__ out)         // (131328, 512)
{
  __shared__ __align__(16) float raw[RAW_ELEMS];
  __shared__ __align__(8)  v2f  pairs[PAIR_ITEMS];   // [row][m]

  const int tid   = threadIdx.x;
  const int b     = blockIdx.y;
  const int chunk = blockIdx.x;      // 0..8
  const float* xb = x + b * (512 * CDIM);

  // ---- tail chunk: the single t=512 row (pair per thread, as before) ----
  if (chunk == 8) {
    const int f0 = 2 * tid, f1 = f0 + 1;
    const int c0 = chan_of(f0), k0 = kidx_of(f0);
    const int c1 = chan_of(f1), k1 = kidx_of(f1);
    v2f acc = {0.f, 0.f};
#pragma unroll
    for (int j = 0; j < 8; ++j) {
      const int p   = 508 + j;
      const bool ok = p < 512;
      const int bse = (ok ? p : 0) * CDIM;
      v2f w;
      w.x = ok ? xb[bse + c0] : 0.f;
      w.y = ok ? xb[bse + c1] : 0.f;
      const v2f kpj = {kern[k0 * 24 + j * 3 + 1], kern[k1 * 24 + j * 3 + 1]};
      acc += w * kpj;
    }
    reinterpret_cast<v2f*>(out + ((size_t)b * TROWS + 512) * 512)[tid] = acc;
    return;
  }

  // ---- per-thread constants: quad f = 4q .. 4q+3, two pair-descriptors ----
  const int q    = tid & 127;
  const int rpar = tid >> 7;          // 2-row interleave
  const int f0   = 4 * q;
  const int m01  = pair_m(f0);
  const int m23  = pair_m(f0 + 2);

  v2f kp01[8], kp23[8];
  {
    const int k0 = kidx_of(f0),     k1 = kidx_of(f0 + 1);
    const int k2 = kidx_of(f0 + 2), k3 = kidx_of(f0 + 3);
#pragma unroll
    for (int j = 0; j < 8; ++j) {
      kp01[j] = (v2f){kern[k0 * 24 + j * 3 + 1], kern[k1 * 24 + j * 3 + 1]};
      kp23[j] = (v2f){kern[k2 * 24 + j * 3 + 1], kern[k3 * 24 + j * 3 + 1]};
    }
  }

  const int t0 = chunk * CHUNK;

  // ---- phase 1: stage raw rows t0-4 .. t0+67 (x7 ch) into LDS ----
  if (chunk >= 1 && chunk <= 6) {
    const v4f* src = reinterpret_cast<const v4f*>(xb + (t0 - 4) * CDIM);
    if (tid < RAW_ELEMS / 4)
      reinterpret_cast<v4f*>(raw)[tid] = src[tid];
  } else {
#pragma unroll
    for (int i = tid; i < RAW_ELEMS; i += 256) {
      const int r = i / CDIM;
      const int c = i - r * CDIM;
      const int p = t0 - 4 + r;
      raw[i] = ((unsigned)p < 512u) ? xb[p * CDIM + c] : 0.f;
    }
  }
  __syncthreads();

  // ---- phase 2: expand each row into the 11 canonical channel pairs ----
#pragma unroll
  for (int item = tid; item < PAIR_ITEMS; item += 256) {
    const int r = item / NPAIRS;
    const int m = item - r * NPAIRS;
    const int cA = (m < 7) ? m : 2 * (m - 7);
    const int cB = (m < 7) ? m : ((m == 10) ? 0 : cA + 1);
    pairs[item] = (v2f){raw[r * CDIM + cA], raw[r * CDIM + cB]};
  }
  __syncthreads();

  // ---- steady loop: 32 steps of 2-row stride ----
  // tap a (a = 0..) of this thread = pairs[(rpar + a)*11 + m]
  const v2f* pp01 = pairs + (rpar * NPAIRS + m01);
  const v2f* pp23 = pairs + (rpar * NPAIRS + m23);

  v2f wp01[8], wp23[8];
#pragma unroll
  for (int j = 0; j < 8; ++j) {
    wp01[j] = pp01[j * NPAIRS];
    wp23[j] = pp23[j * NPAIRS];
  }

  v4f* orow =
      reinterpret_cast<v4f*>(out + ((size_t)b * TROWS + t0 + rpar) * 512) + q;

#pragma unroll 1
  for (int g = 0; g < 8; ++g) {        // 8 groups x 4 steps = 32 steps
#pragma unroll
    for (int u = 0; u < 4; ++u) {
      const int base = 2 * u;          // window rotation (compile-time)

      // prefetch the 2 new tap rows for each descriptor (ds_read_b64 x4)
      const v2f n01a = pp01[(base + 8) * NPAIRS];
      const v2f n01b = pp01[(base + 9) * NPAIRS];
      const v2f n23a = pp23[(base + 8) * NPAIRS];
      const v2f n23b = pp23[(base + 9) * NPAIRS];

      v2f a01 = {0.f, 0.f}, a23 = {0.f, 0.f};
#pragma unroll
      for (int j = 0; j < 8; ++j) {
        a01 += wp01[(base + j) & 7] * kp01[j];   // v_pk_fma_f32, all useful
        a23 += wp23[(base + j) & 7] * kp23[j];
      }
      const v4f o = {a01.x, a01.y, a23.x, a23.y};
      *orow = o;                        // ONE dwordx4: 16B/lane, 1KB/wave
      orow += 2 * 128;                  // advance 2 rows

      wp01[base & 7]       = n01a;
      wp01[(base + 1) & 7] = n01b;
      wp23[base & 7]       = n23a;
      wp23[(base + 1) & 7] = n23b;
    }
    pp01 += 8 * NPAIRS;                 // 4 steps x 2 rows
    pp23 += 8 * NPAIRS;
  }
}

extern "C" void kernel_launch(void* const* d_in, const int* in_sizes, int n_in,
                              void* d_out, int out_size, void* d_ws, size_t ws_size,
                              hipStream_t stream) {
  const float* x    = (const float*)d_in[0];
  const float* kern = (const float*)d_in[1];
  float* out        = (float*)d_out;

  dim3 grid(9, 256);   // chunks 0..7: 64-row stream; chunk 8: t=512 row
  tok_conv_kernel<<<grid, 256, 0, stream>>>(x, kern, out);
}

// Round 10
// 57.494 us; speedup vs baseline: 1.0818x; 1.0818x over previous
//
#include <hip/hip_runtime.h>

// TokenEmbedding_51153060495497
// x: (256, 512, 7) f32;  kernels: (74, 8, 3) f32; keff = kernels[:,:,1]
// out flat: (256*513, 512) f32
//   row r = b*513 + t;  f in [0,512):
//     f < 511 : c = f/73, k = f%73
//     f == 511: c = 0,    k = 73
//   out[r*512+f] = sum_j xp[b, t+j-4, c] * keff[k, j]  (xp zero outside [0,512))
//
// r8 structure (pair/thread, scalar sliding window, 8 waves/SIMD) + LDS
// write-combining: 4-row double-buffered output tile in LDS, dumped as
// aligned global_store_dwordx4 (16B/lane) to test the store-address-rate
// ceiling at fixed occupancy.

typedef float v2f __attribute__((ext_vector_type(2)));
typedef float v4f __attribute__((ext_vector_type(4)));

#define CDIM 7
#define TROWS 513
#define CHUNK 64
#define WIN_ROWS 72                    // CHUNK + 8
#define RAW_ELEMS (WIN_ROWS * CDIM)    // 504 floats = 126 float4

__device__ __forceinline__ int chan_of(int f) { return (f == 511) ? 0 : (f / 73); }
__device__ __forceinline__ int kidx_of(int f) { return (f == 511) ? 73 : (f % 73); }

__global__ __launch_bounds__(256, 8) void tok_conv_kernel(
    const float* __restrict__ x,     // (256,512,7)
    const float* __restrict__ kern,  // (74,8,3)
    float* __restrict__ out)         // (131328, 512)
{
  __shared__ __align__(16) float raw[RAW_ELEMS];
  __shared__ __align__(16) float buf0[4 * 512];   // 8 KB
  __shared__ __align__(16) float buf1[4 * 512];   // 8 KB

  const int tid   = threadIdx.x;     // pair index 0..255
  const int b     = blockIdx.y;
  const int chunk = blockIdx.x;      // 0..8
  const float* xb = x + b * (512 * CDIM);

  const int f0 = 2 * tid, f1 = f0 + 1;
  const int c0 = chan_of(f0), k0 = kidx_of(f0);
  const int c1 = chan_of(f1), k1 = kidx_of(f1);

  // packed weights: kp[j] = (keff[k0][j], keff[k1][j]) — no zero slots
  v2f kp[8];
#pragma unroll
  for (int j = 0; j < 8; ++j)
    kp[j] = (v2f){kern[k0 * 24 + j * 3 + 1], kern[k1 * 24 + j * 3 + 1]};

  // ---- tail chunk: the single t=512 row ----
  if (chunk == 8) {
    v2f acc = {0.f, 0.f};
#pragma unroll
    for (int j = 0; j < 8; ++j) {
      const int p   = 508 + j;          // t=512: taps p = 508..515
      const bool ok = p < 512;
      const int bse = (ok ? p : 0) * CDIM;
      v2f w;
      w.x = ok ? xb[bse + c0] : 0.f;
      w.y = ok ? xb[bse + c1] : 0.f;
      acc += w * kp[j];
    }
    reinterpret_cast<v2f*>(out + ((size_t)b * TROWS + 512) * 512)[tid] = acc;
    return;
  }

  const int t0 = chunk * CHUNK;

  // ---- stage rows t0-4 .. t0+67 (x7 ch) into LDS ----
  if (chunk >= 1 && chunk <= 6) {
    const v4f* src = reinterpret_cast<const v4f*>(xb + (t0 - 4) * CDIM);
    if (tid < RAW_ELEMS / 4)
      reinterpret_cast<v4f*>(raw)[tid] = src[tid];
  } else {
#pragma unroll
    for (int i = tid; i < RAW_ELEMS; i += 256) {
      const int r = i / CDIM;
      const int c = i - r * CDIM;
      const int p = t0 - 4 + r;
      raw[i] = ((unsigned)p < 512u) ? xb[p * CDIM + c] : 0.f;
    }
  }
  __syncthreads();

  int bx0 = c0, bx1 = c1;            // window bases, advance 8 rows per macro

  // initial window: rows 0..7
  v2f w[8];
#pragma unroll
  for (int j = 0; j < 8; ++j)
    w[j] = (v2f){raw[bx0 + j * CDIM], raw[bx1 + j * CDIM]};

  v2f*       sb0 = reinterpret_cast<v2f*>(buf0) + tid;   // row stride 256 v2f
  v2f*       sb1 = reinterpret_cast<v2f*>(buf1) + tid;
  const v4f* rb0 = reinterpret_cast<const v4f*>(buf0);
  const v4f* rb1 = reinterpret_cast<const v4f*>(buf1);
  v4f* dptr = reinterpret_cast<v4f*>(out + ((size_t)b * TROWS + t0) * 512);

#pragma unroll 1
  for (int m = 0; m < 8; ++m) {      // 8 macro-iters x 8 rows = 64 rows
    // ---- half A: dump buf1 (rows 8m-4..8m-1), compute rows 8m..8m+3 -> buf0
    if (m) {
      dptr[tid]       = rb1[tid];        // ds_read_b128 + store_dwordx4
      dptr[tid + 256] = rb1[tid + 256];
      dptr += 512;                       // advance 4 rows
    }
#pragma unroll
    for (int u = 0; u < 4; ++u) {
      v2f nv = {raw[bx0 + (u + 8) * CDIM], raw[bx1 + (u + 8) * CDIM]};
      v2f acc = {0.f, 0.f};
#pragma unroll
      for (int j = 0; j < 8; ++j)
        acc += w[(u + j) & 7] * kp[j];   // v_pk_fma_f32, both slots useful
      sb0[u * 256] = acc;                // ds_write_b64, 2-way alias (free)
      w[u] = nv;                         // slot u&7 == u
    }
    __syncthreads();

    // ---- half B: dump buf0 (rows 8m..8m+3), compute rows 8m+4..8m+7 -> buf1
    dptr[tid]       = rb0[tid];
    dptr[tid + 256] = rb0[tid + 256];
    dptr += 512;
#pragma unroll
    for (int u = 4; u < 8; ++u) {
      v2f nv = {raw[bx0 + (u + 8) * CDIM], raw[bx1 + (u + 8) * CDIM]};
      v2f acc = {0.f, 0.f};
#pragma unroll
      for (int j = 0; j < 8; ++j)
        acc += w[(u + j) & 7] * kp[j];
      sb1[(u - 4) * 256] = acc;
      w[u] = nv;                         // slot u&7 == u
    }
    bx0 += 8 * CDIM;
    bx1 += 8 * CDIM;
    __syncthreads();
  }

  // epilogue: dump buf1 (rows 60..63)
  dptr[tid]       = rb1[tid];
  dptr[tid + 256] = rb1[tid + 256];
}

extern "C" void kernel_launch(void* const* d_in, const int* in_sizes, int n_in,
                              void* d_out, int out_size, void* d_ws, size_t ws_size,
                              hipStream_t stream) {
  const float* x    = (const float*)d_in[0];
  const float* kern = (const float*)d_in[1];
  float* out        = (float*)d_out;

  dim3 grid(9, 256);   // chunks 0..7: 64-row stream; chunk 8: t=512 row
  tok_conv_kernel<<<grid, 256, 0, stream>>>(x, kern, out);
}